// Round 14
// baseline (209.229 us; speedup 1.0000x reference)
//
#include <hip/hip_runtime.h>
#include <math.h>

// Problem constants (from reference)
#define BB 2
#define LL 1024
#define CC 1024
#define HH 8
#define DD 128          // C / H
#define SS 32           // sample taps
#define HALF_S 16
#define KK 64           // kernel taps

// ===========================================================================
// FROZEN NUMERICS (do not touch):
//  - wave dot: sequential fp32 FMA chain, k ascending, single accumulator
//  - sigmoid/tanh: correctly-rounded fp32 via fp64
//  - census distance math + lexicographic (dist-bits, packed-idx) argmin
//  - gather decision chain (_rn ops, no FMA contraction) + surgical flip
//  - GEMM: v4 schedule exactly — measured floor (v5-v10 regressed/neutral).
// R13 state (201.6us best): fused wave(LDS-staged)+kmat GEMM @768 blocks,
// gather v5 (4-s-deep batch), final GEMM v4, memset init.
// v16 = R13 with gather v6: batch depth 4 -> 8 (8 tab reads, 16 global b128
// in flight, consume ascending s). R10 (TLP 2x: +2.5us) vs R13 (MLP 4-deep:
// +8us) says depth beats occupancy here; trade ~half the waves for 2x
// in-flight loads. Same loads/values/order -> bit-identical y.
// ===========================================================================

// ---------------------------------------------------------------------------
// SGEMM v4 body (verified 66 us floor) as a device function.
// ---------------------------------------------------------------------------
template <int TM>
__device__ __forceinline__ void sgemm_body(
    const float* __restrict__ A, const float* __restrict__ Bw,
    const float* __restrict__ bias, float* __restrict__ Cm,
    int M, int N, int Kd, int bx, int by) {
  const int RM = TM / 16;                 // rows per thread: 4 or 2
  __shared__ float As[2][16][TM + 4];
  __shared__ float Bs[2][16][64 + 4];
  int tid = threadIdx.x;                  // 0..255
  int tx = tid & 15;                      // col group (4 cols)
  int ty = tid >> 4;                      // row group (RM rows)
  int row0 = by * TM;
  int col0 = bx * 64;
  int r = tid >> 2;                       // 0..63
  int cq = (tid & 3) << 2;                // 0,4,8,12
  const bool aload = (TM == 64) || (r < TM);
  float acc[RM][4];
#pragma unroll
  for (int i = 0; i < RM; ++i)
#pragma unroll
    for (int jj = 0; jj < 4; ++jj) acc[i][jj] = 0.f;

  // prologue: stage tile 0
  {
    float4 av = aload ? *(const float4*)&A[(size_t)(row0 + r) * Kd + cq]
                      : make_float4(0.f, 0.f, 0.f, 0.f);
    float4 bv = *(const float4*)&Bw[(size_t)(col0 + r) * Kd + cq];
    if (aload) {
      As[0][cq + 0][r] = av.x; As[0][cq + 1][r] = av.y;
      As[0][cq + 2][r] = av.z; As[0][cq + 3][r] = av.w;
    }
    Bs[0][cq + 0][r] = bv.x; Bs[0][cq + 1][r] = bv.y;
    Bs[0][cq + 2][r] = bv.z; Bs[0][cq + 3][r] = bv.w;
  }
  __syncthreads();

  int buf = 0;
  for (int k0 = 0; k0 < Kd; k0 += 16) {
    bool have_next = (k0 + 16) < Kd;
    float4 av, bv;
    if (have_next) {
      if (aload) av = *(const float4*)&A[(size_t)(row0 + r) * Kd + k0 + 16 + cq];
      bv = *(const float4*)&Bw[(size_t)(col0 + r) * Kd + k0 + 16 + cq];
    }
#pragma unroll
    for (int kk = 0; kk < 16; ++kk) {
      float a[RM], b[4];
      if (RM == 4) {
        float4 a4 = *(const float4*)&As[buf][kk][ty * 4];
        a[0] = a4.x; a[1] = a4.y; a[2] = a4.z; a[3] = a4.w;
      } else {
        float2 a2 = *(const float2*)&As[buf][kk][ty * 2];
        a[0] = a2.x; a[1] = a2.y;
      }
      float4 b4 = *(const float4*)&Bs[buf][kk][tx * 4];
      b[0] = b4.x; b[1] = b4.y; b[2] = b4.z; b[3] = b4.w;
#pragma unroll
      for (int i = 0; i < RM; ++i)
#pragma unroll
        for (int jj = 0; jj < 4; ++jj)
          acc[i][jj] = __fmaf_rn(a[i], b[jj], acc[i][jj]);
    }
    if (have_next) {
      int nb = buf ^ 1;
      if (aload) {
        As[nb][cq + 0][r] = av.x; As[nb][cq + 1][r] = av.y;
        As[nb][cq + 2][r] = av.z; As[nb][cq + 3][r] = av.w;
      }
      Bs[nb][cq + 0][r] = bv.x; Bs[nb][cq + 1][r] = bv.y;
      Bs[nb][cq + 2][r] = bv.z; Bs[nb][cq + 3][r] = bv.w;
    }
    __syncthreads();
    buf ^= 1;
  }
#pragma unroll
  for (int i = 0; i < RM; ++i) {
    int rr = row0 + ty * RM + i;
    int c = col0 + tx * 4;
    float4 v;
    v.x = acc[i][0]; v.y = acc[i][1]; v.z = acc[i][2]; v.w = acc[i][3];
    if (bias) {
      v.x += bias[c + 0]; v.y += bias[c + 1];
      v.z += bias[c + 2]; v.w += bias[c + 3];
    }
    *(float4*)&Cm[(size_t)rr * N + c] = v;
  }
}

// ---------------------------------------------------------------------------
// Fat kernel, grid 768 (3 blocks/CU uniform):
//  bid < 512 : kmat GEMM (v4 TM=32 body), bx=bid&7, by=bid>>3.
//  bid >= 512: wave block, 8 positions, tid<128 active (2 full waves),
//    wave_w staged via LDS in 2 passes of 512 columns (R12 win).
// ---------------------------------------------------------------------------
__global__ __launch_bounds__(256) void fused_wave_sgemm(
    const float* __restrict__ x, const float* __restrict__ wave_w,
    const float* __restrict__ wave_b, float* __restrict__ freq_out,
    float* __restrict__ phase_out, unsigned long long* __restrict__ cell,
    const float* __restrict__ kernel_w, const float* __restrict__ kernel_b,
    float* __restrict__ kmat, int M, int N, int Kd) {
  int bid = blockIdx.x;
  if (bid < 512) {
    sgemm_body<32>(x, kernel_w, kernel_b, kmat, M, N, Kd, bid & 7, bid >> 3);
    return;
  }
  // ---- wave path: FROZEN numerics; wv values via LDS copy ----
  __shared__ float ws[16][516];          // 512 cols + pad4 (2-way banks)
  int tid = threadIdx.x;                 // 0..255; tid<128 compute-active
  int wb = bid - 512;                    // 0..255
  int j = tid & 15;                      // which of the 16 wave outputs
  int p = wb * 8 + (tid >> 4);           // valid (deref'd) only for tid<128
  const float* xr = x + (size_t)p * CC;
  float acc = 0.f;
  for (int kb = 0; kb < CC; kb += 512) {
    // stage wave_w[:, kb..kb+511] (all 256 threads, coalesced)
    for (int idx = tid; idx < 16 * 128; idx += 256) {
      int row = idx >> 7;                // 0..15
      int c4  = (idx & 127) << 2;        // 0..508
      float4 v = *(const float4*)&wave_w[(size_t)row * CC + kb + c4];
      ws[row][c4 + 0] = v.x; ws[row][c4 + 1] = v.y;
      ws[row][c4 + 2] = v.z; ws[row][c4 + 3] = v.w;
    }
    __syncthreads();
    if (tid < 128) {
#pragma unroll 4
      for (int k = 0; k < 512; k += 4) {
        float4 xv = *(const float4*)&xr[kb + k];
        float4 wv = *(const float4*)&ws[j][k];
        acc = __fmaf_rn(xv.x, wv.x, acc);    // FROZEN: same chain, same vals
        acc = __fmaf_rn(xv.y, wv.y, acc);
        acc = __fmaf_rn(xv.z, wv.z, acc);
        acc = __fmaf_rn(xv.w, wv.w, acc);
      }
    }
    __syncthreads();
  }
  if (tid >= 128) return;                // waves 2,3 done (staging only)
  acc = __fadd_rn(acc, wave_b[j]);
  int base = tid & 48;                   // lane-local group of 16
  int hh = j & 7;
  float w0 = __shfl(acc, base + 2 * hh);
  float w1 = __shfl(acc, base + 2 * hh + 1);
  unsigned long long key = ~0ULL;
  if (j < 8) {
    float e  = (float)exp(-(double)w0);          // FROZEN: CR fp32 exp
    float sg = __fdiv_rn(1.0f, __fadd_rn(1.0f, e));
    float fr = __fadd_rn(1.0f, __fmul_rn(sg, 15.0f));
    float th = (float)tanh((double)w1);          // FROZEN: CR fp32 tanh
    float ph = __fmul_rn(th, fr);
    freq_out[p * HH + hh] = fr;
    phase_out[p * HH + hh] = ph;
#pragma unroll
    for (int s = 0; s < SS; ++s) {
      float tap = (float)s - 15.5f;
      float off = __fadd_rn(ph, __fmul_rn(fr, tap));
      float dc  = __fmul_rn(__fadd_rn(off, 256.0f), 0.125f);
      float fl  = floorf(dc);
      float t   = __fsub_rn(dc, fl);
      int bin   = max(0, min((int)fl, KK - 1));
      int altr  = (t < 0.5f) ? (int)fl - 1 : (int)fl + 1;
      int alt   = max(0, min(altr, KK - 1));
      float dist = fminf(t, 1.0f - t);
      if (alt == bin) dist = 1.0f;               // clamp no-op: exclude
      unsigned int bits = __float_as_uint(dist);
      unsigned long long k2 = ((unsigned long long)bits << 32) |
                              (unsigned int)(p * 256 + hh * 32 + s);
      key = (k2 < key) ? k2 : key;
    }
  }
#pragma unroll
  for (int w = 32; w > 0; w >>= 1) {     // butterfly on full waves 0,1
    unsigned int lo = (unsigned int)(key & 0xFFFFFFFFull);
    unsigned int hi = (unsigned int)(key >> 32);
    unsigned int lo2 = __shfl_xor(lo, w);
    unsigned int hi2 = __shfl_xor(hi, w);
    unsigned long long other = ((unsigned long long)hi2 << 32) | lo2;
    key = (other < key) ? other : key;
  }
  if ((tid & 63) == 0) atomicMin(cell, key);     // one per wave; same min
}

// Standalone GEMM for the final projection (v4 TM=64, unchanged).
__global__ __launch_bounds__(256) void sgemm_nt_v4_64(
    const float* __restrict__ A, const float* __restrict__ Bw,
    float* __restrict__ Cm, int M, int N, int Kd) {
  sgemm_body<64>(A, Bw, nullptr, Cm, M, N, Kd, blockIdx.x, blockIdx.y);
}

// ---------------------------------------------------------------------------
// Kernel 3: gather v6 = v5 with batch depth 8: per group, 8 s_tab reads ->
// 16 global b128 in flight -> consume ascending s. Same addresses, values,
// and _rn lerp/FMA order -> bit-identical.
// ---------------------------------------------------------------------------
__global__ __launch_bounds__(256) void gather_kernel(
    const float* __restrict__ x, const float* __restrict__ freq_a,
    const float* __restrict__ phase_a, const float* __restrict__ kmat,
    const unsigned long long* __restrict__ cell,
    float* __restrict__ y) {
  int i = blockIdx.x;                 // 0..2047
  int p = ((i & 7) << 8) + (i >> 3);  // XCD-contiguous position mapping
  int b = p / LL;
  int l = p - b * LL;
  int d = threadIdx.x;  // 0..255
  __shared__ float4 s_tab[HH * SS];   // {i0 bits, i1 bits, frac, w}
  unsigned int argmin_idx = (unsigned int)(*cell & 0xFFFFFFFFull);
  const float* xb = x + (size_t)b * LL * CC;
  {
    int slot = d;                     // one slot per thread (256 slots)
    int h = slot >> 5;
    int s = slot & 31;
    float fr = freq_a[p * HH + h];
    float ph = phase_a[p * HH + h];
    float tap = (float)s - 15.5f;                       // FROZEN chain:
    float off = __fadd_rn(ph, __fmul_rn(fr, tap));      // mul rnd, add rnd
    float pos = __fadd_rn((float)l, off);
    pos = fminf(fmaxf(pos, 0.0f), 1023.0f);
    float i0f = floorf(pos);
    float frac = __fsub_rn(pos, i0f);
    int i0 = (int)i0f;
    int i1 = min(i0 + 1, LL - 1);
    float dc = __fmul_rn(__fadd_rn(off, 256.0f), 0.125f);
    float fl = floorf(dc);
    float t  = __fsub_rn(dc, fl);
    int bin  = max(0, min((int)fl, KK - 1));
    unsigned int packed = (unsigned int)((p << 8) | slot);
    if (packed == argmin_idx) {
      int altr = (t < 0.5f) ? (int)fl - 1 : (int)fl + 1;
      bin = max(0, min(altr, KK - 1));      // surgical flip (FROZEN)
    }
    float wv = kmat[((size_t)p * HH + h) * KK + bin];
    s_tab[slot] = make_float4(__int_as_float(i0), __int_as_float(i1), frac, wv);
  }
  __syncthreads();
  int q = d & 31;             // d-quad: covers d = q*4 .. q*4+3
  int h = d >> 5;             // one head per thread (0..7)
  const int hb = h * SS;
  const float* xh = xb + h * DD + q * 4;
  float4 acc = make_float4(0.f, 0.f, 0.f, 0.f);

#define LERP_FMA(TB, G0, G1)                                               \
  {                                                                        \
    float frac = TB.z;                                                     \
    float w = TB.w;                                                        \
    float gx = __fadd_rn(G0.x, __fmul_rn(frac, __fsub_rn(G1.x, G0.x)));    \
    float gy = __fadd_rn(G0.y, __fmul_rn(frac, __fsub_rn(G1.y, G0.y)));    \
    float gz = __fadd_rn(G0.z, __fmul_rn(frac, __fsub_rn(G1.z, G0.z)));    \
    float gw = __fadd_rn(G0.w, __fmul_rn(frac, __fsub_rn(G1.w, G0.w)));    \
    acc.x = __fmaf_rn(w, gx, acc.x);                                       \
    acc.y = __fmaf_rn(w, gy, acc.y);                                       \
    acc.z = __fmaf_rn(w, gz, acc.z);                                       \
    acc.w = __fmaf_rn(w, gw, acc.w);                                       \
  }

#pragma unroll
  for (int sg = 0; sg < SS; sg += 8) {
    // batch: 8 tab reads, then 16 global loads in flight, then consume
    float4 tb0 = s_tab[hb + sg + 0];
    float4 tb1 = s_tab[hb + sg + 1];
    float4 tb2 = s_tab[hb + sg + 2];
    float4 tb3 = s_tab[hb + sg + 3];
    float4 tb4 = s_tab[hb + sg + 4];
    float4 tb5 = s_tab[hb + sg + 5];
    float4 tb6 = s_tab[hb + sg + 6];
    float4 tb7 = s_tab[hb + sg + 7];
    float4 g00 = *(const float4*)&xh[(size_t)__float_as_int(tb0.x) * CC];
    float4 g01 = *(const float4*)&xh[(size_t)__float_as_int(tb0.y) * CC];
    float4 g10 = *(const float4*)&xh[(size_t)__float_as_int(tb1.x) * CC];
    float4 g11 = *(const float4*)&xh[(size_t)__float_as_int(tb1.y) * CC];
    float4 g20 = *(const float4*)&xh[(size_t)__float_as_int(tb2.x) * CC];
    float4 g21 = *(const float4*)&xh[(size_t)__float_as_int(tb2.y) * CC];
    float4 g30 = *(const float4*)&xh[(size_t)__float_as_int(tb3.x) * CC];
    float4 g31 = *(const float4*)&xh[(size_t)__float_as_int(tb3.y) * CC];
    float4 g40 = *(const float4*)&xh[(size_t)__float_as_int(tb4.x) * CC];
    float4 g41 = *(const float4*)&xh[(size_t)__float_as_int(tb4.y) * CC];
    float4 g50 = *(const float4*)&xh[(size_t)__float_as_int(tb5.x) * CC];
    float4 g51 = *(const float4*)&xh[(size_t)__float_as_int(tb5.y) * CC];
    float4 g60 = *(const float4*)&xh[(size_t)__float_as_int(tb6.x) * CC];
    float4 g61 = *(const float4*)&xh[(size_t)__float_as_int(tb6.y) * CC];
    float4 g70 = *(const float4*)&xh[(size_t)__float_as_int(tb7.x) * CC];
    float4 g71 = *(const float4*)&xh[(size_t)__float_as_int(tb7.y) * CC];
    LERP_FMA(tb0, g00, g01)              // s ascending — FROZEN chain
    LERP_FMA(tb1, g10, g11)
    LERP_FMA(tb2, g20, g21)
    LERP_FMA(tb3, g30, g31)
    LERP_FMA(tb4, g40, g41)
    LERP_FMA(tb5, g50, g51)
    LERP_FMA(tb6, g60, g61)
    LERP_FMA(tb7, g70, g71)
  }
#undef LERP_FMA
  *(float4*)&y[(size_t)p * CC + h * DD + q * 4] = acc;
}

// ---------------------------------------------------------------------------
extern "C" void kernel_launch(void* const* d_in, const int* in_sizes, int n_in,
                              void* d_out, int out_size, void* d_ws, size_t ws_size,
                              hipStream_t stream) {
  const float* x        = (const float*)d_in[0];
  const float* wave_w   = (const float*)d_in[1];
  const float* wave_b   = (const float*)d_in[2];
  const float* kernel_w = (const float*)d_in[3];
  const float* kernel_b = (const float*)d_in[4];
  const float* out_w    = (const float*)d_in[5];
  float* out = (float*)d_out;

  float* freq  = (float*)d_ws;                         // 16384 floats
  float* phase = freq + BB * LL * HH;                  // 16384 floats
  unsigned long long* cell =
      (unsigned long long*)(phase + BB * LL * HH);     // 1 u64 (8B aligned)
  float* kmat  = (float*)(cell + 1);                   // 1M floats (4 MB)
  float* y     = kmat + (size_t)BB * LL * HH * KK;     // 2M floats (8 MB)

  const int M = BB * LL;  // 2048

  hipMemsetAsync(cell, 0xFF, sizeof(unsigned long long), stream);  // ~0ULL

  fused_wave_sgemm<<<768, 256, 0, stream>>>(
      x, wave_w, wave_b, freq, phase, cell,
      kernel_w, kernel_b, kmat, M, HH * KK, CC);

  gather_kernel<<<M, 256, 0, stream>>>(x, freq, phase, kmat, cell, y);

  dim3 g4(CC / 64, M / 64);  // (16, 32) = 512 blocks
  sgemm_nt_v4_64<<<g4, 256, 0, stream>>>(y, out_w, out, M, CC, CC);
}

// Round 15
// 202.188 us; speedup vs baseline: 1.0348x; 1.0348x over previous
//
#include <hip/hip_runtime.h>
#include <math.h>

// Problem constants (from reference)
#define BB 2
#define LL 1024
#define CC 1024
#define HH 8
#define DD 128          // C / H
#define SS 32           // sample taps
#define HALF_S 16
#define KK 64           // kernel taps

// ===========================================================================
// FROZEN NUMERICS (do not touch):
//  - wave dot: sequential fp32 FMA chain, k ascending, single accumulator
//  - sigmoid/tanh: correctly-rounded fp32 via fp64
//  - census distance math + lexicographic (dist-bits, packed-idx) argmin
//  - gather decision chain (_rn ops, no FMA contraction) + surgical flip
//  - GEMM: v4 schedule exactly — measured floor (v5-v10 regressed/neutral).
// R13 state (201.6us best): fused wave(LDS-staged)+kmat GEMM @768 blocks,
// gather v5 (4-s-deep batch; 8-deep regressed R14), final GEMM v4.
// v17 = R13 + XCD-L2-resident block tiling for both GEMMs (index remap only):
//  - GEMM64: 8x8 block tile per XCD -> 2MB y + 2MB out_w resident in the
//    4MB XCD L2 (was: all 8MB y per XCD -> 3x HBM refetch, FETCH 35.9MB).
//  - kmat GEMM: 8 by-rows + all bx per XCD -> 1MB x + 2MB kernel_w.
// Bijective remaps; per-output work unchanged -> bit-identical outputs.
// ===========================================================================

// ---------------------------------------------------------------------------
// SGEMM v4 body (verified 66 us floor) as a device function.
// ---------------------------------------------------------------------------
template <int TM>
__device__ __forceinline__ void sgemm_body(
    const float* __restrict__ A, const float* __restrict__ Bw,
    const float* __restrict__ bias, float* __restrict__ Cm,
    int M, int N, int Kd, int bx, int by) {
  const int RM = TM / 16;                 // rows per thread: 4 or 2
  __shared__ float As[2][16][TM + 4];
  __shared__ float Bs[2][16][64 + 4];
  int tid = threadIdx.x;                  // 0..255
  int tx = tid & 15;                      // col group (4 cols)
  int ty = tid >> 4;                      // row group (RM rows)
  int row0 = by * TM;
  int col0 = bx * 64;
  int r = tid >> 2;                       // 0..63
  int cq = (tid & 3) << 2;                // 0,4,8,12
  const bool aload = (TM == 64) || (r < TM);
  float acc[RM][4];
#pragma unroll
  for (int i = 0; i < RM; ++i)
#pragma unroll
    for (int jj = 0; jj < 4; ++jj) acc[i][jj] = 0.f;

  // prologue: stage tile 0
  {
    float4 av = aload ? *(const float4*)&A[(size_t)(row0 + r) * Kd + cq]
                      : make_float4(0.f, 0.f, 0.f, 0.f);
    float4 bv = *(const float4*)&Bw[(size_t)(col0 + r) * Kd + cq];
    if (aload) {
      As[0][cq + 0][r] = av.x; As[0][cq + 1][r] = av.y;
      As[0][cq + 2][r] = av.z; As[0][cq + 3][r] = av.w;
    }
    Bs[0][cq + 0][r] = bv.x; Bs[0][cq + 1][r] = bv.y;
    Bs[0][cq + 2][r] = bv.z; Bs[0][cq + 3][r] = bv.w;
  }
  __syncthreads();

  int buf = 0;
  for (int k0 = 0; k0 < Kd; k0 += 16) {
    bool have_next = (k0 + 16) < Kd;
    float4 av, bv;
    if (have_next) {
      if (aload) av = *(const float4*)&A[(size_t)(row0 + r) * Kd + k0 + 16 + cq];
      bv = *(const float4*)&Bw[(size_t)(col0 + r) * Kd + k0 + 16 + cq];
    }
#pragma unroll
    for (int kk = 0; kk < 16; ++kk) {
      float a[RM], b[4];
      if (RM == 4) {
        float4 a4 = *(const float4*)&As[buf][kk][ty * 4];
        a[0] = a4.x; a[1] = a4.y; a[2] = a4.z; a[3] = a4.w;
      } else {
        float2 a2 = *(const float2*)&As[buf][kk][ty * 2];
        a[0] = a2.x; a[1] = a2.y;
      }
      float4 b4 = *(const float4*)&Bs[buf][kk][tx * 4];
      b[0] = b4.x; b[1] = b4.y; b[2] = b4.z; b[3] = b4.w;
#pragma unroll
      for (int i = 0; i < RM; ++i)
#pragma unroll
        for (int jj = 0; jj < 4; ++jj)
          acc[i][jj] = __fmaf_rn(a[i], b[jj], acc[i][jj]);
    }
    if (have_next) {
      int nb = buf ^ 1;
      if (aload) {
        As[nb][cq + 0][r] = av.x; As[nb][cq + 1][r] = av.y;
        As[nb][cq + 2][r] = av.z; As[nb][cq + 3][r] = av.w;
      }
      Bs[nb][cq + 0][r] = bv.x; Bs[nb][cq + 1][r] = bv.y;
      Bs[nb][cq + 2][r] = bv.z; Bs[nb][cq + 3][r] = bv.w;
    }
    __syncthreads();
    buf ^= 1;
  }
#pragma unroll
  for (int i = 0; i < RM; ++i) {
    int rr = row0 + ty * RM + i;
    int c = col0 + tx * 4;
    float4 v;
    v.x = acc[i][0]; v.y = acc[i][1]; v.z = acc[i][2]; v.w = acc[i][3];
    if (bias) {
      v.x += bias[c + 0]; v.y += bias[c + 1];
      v.z += bias[c + 2]; v.w += bias[c + 3];
    }
    *(float4*)&Cm[(size_t)rr * N + c] = v;
  }
}

// ---------------------------------------------------------------------------
// Fat kernel, grid 768 (3 blocks/CU uniform):
//  bid < 512 : kmat GEMM, XCD-tiled: xcd=bid&7 owns by in [xcd*8,xcd*8+8)
//    and all 8 bx -> 1MB x-rows + 2MB kernel_w per XCD L2 (was all 8MB x).
//  bid >= 512: wave block, 8 positions, tid<128 active (2 full waves),
//    wave_w staged via LDS in 2 passes of 512 columns (R12 win).
// ---------------------------------------------------------------------------
__global__ __launch_bounds__(256) void fused_wave_sgemm(
    const float* __restrict__ x, const float* __restrict__ wave_w,
    const float* __restrict__ wave_b, float* __restrict__ freq_out,
    float* __restrict__ phase_out, unsigned long long* __restrict__ cell,
    const float* __restrict__ kernel_w, const float* __restrict__ kernel_b,
    float* __restrict__ kmat, int M, int N, int Kd) {
  int bid = blockIdx.x;
  if (bid < 512) {
    int xcd = bid & 7;
    int l   = bid >> 3;                  // 0..63
    int by  = xcd * 8 + (l & 7);         // 0..63, contiguous per XCD
    int bx  = l >> 3;                    // 0..7
    sgemm_body<32>(x, kernel_w, kernel_b, kmat, M, N, Kd, bx, by);
    return;
  }
  // ---- wave path: FROZEN numerics; wv values via LDS copy ----
  __shared__ float ws[16][516];          // 512 cols + pad4 (2-way banks)
  int tid = threadIdx.x;                 // 0..255; tid<128 compute-active
  int wb = bid - 512;                    // 0..255
  int j = tid & 15;                      // which of the 16 wave outputs
  int p = wb * 8 + (tid >> 4);           // valid (deref'd) only for tid<128
  const float* xr = x + (size_t)p * CC;
  float acc = 0.f;
  for (int kb = 0; kb < CC; kb += 512) {
    // stage wave_w[:, kb..kb+511] (all 256 threads, coalesced)
    for (int idx = tid; idx < 16 * 128; idx += 256) {
      int row = idx >> 7;                // 0..15
      int c4  = (idx & 127) << 2;        // 0..508
      float4 v = *(const float4*)&wave_w[(size_t)row * CC + kb + c4];
      ws[row][c4 + 0] = v.x; ws[row][c4 + 1] = v.y;
      ws[row][c4 + 2] = v.z; ws[row][c4 + 3] = v.w;
    }
    __syncthreads();
    if (tid < 128) {
#pragma unroll 4
      for (int k = 0; k < 512; k += 4) {
        float4 xv = *(const float4*)&xr[kb + k];
        float4 wv = *(const float4*)&ws[j][k];
        acc = __fmaf_rn(xv.x, wv.x, acc);    // FROZEN: same chain, same vals
        acc = __fmaf_rn(xv.y, wv.y, acc);
        acc = __fmaf_rn(xv.z, wv.z, acc);
        acc = __fmaf_rn(xv.w, wv.w, acc);
      }
    }
    __syncthreads();
  }
  if (tid >= 128) return;                // waves 2,3 done (staging only)
  acc = __fadd_rn(acc, wave_b[j]);
  int base = tid & 48;                   // lane-local group of 16
  int hh = j & 7;
  float w0 = __shfl(acc, base + 2 * hh);
  float w1 = __shfl(acc, base + 2 * hh + 1);
  unsigned long long key = ~0ULL;
  if (j < 8) {
    float e  = (float)exp(-(double)w0);          // FROZEN: CR fp32 exp
    float sg = __fdiv_rn(1.0f, __fadd_rn(1.0f, e));
    float fr = __fadd_rn(1.0f, __fmul_rn(sg, 15.0f));
    float th = (float)tanh((double)w1);          // FROZEN: CR fp32 tanh
    float ph = __fmul_rn(th, fr);
    freq_out[p * HH + hh] = fr;
    phase_out[p * HH + hh] = ph;
#pragma unroll
    for (int s = 0; s < SS; ++s) {
      float tap = (float)s - 15.5f;
      float off = __fadd_rn(ph, __fmul_rn(fr, tap));
      float dc  = __fmul_rn(__fadd_rn(off, 256.0f), 0.125f);
      float fl  = floorf(dc);
      float t   = __fsub_rn(dc, fl);
      int bin   = max(0, min((int)fl, KK - 1));
      int altr  = (t < 0.5f) ? (int)fl - 1 : (int)fl + 1;
      int alt   = max(0, min(altr, KK - 1));
      float dist = fminf(t, 1.0f - t);
      if (alt == bin) dist = 1.0f;               // clamp no-op: exclude
      unsigned int bits = __float_as_uint(dist);
      unsigned long long k2 = ((unsigned long long)bits << 32) |
                              (unsigned int)(p * 256 + hh * 32 + s);
      key = (k2 < key) ? k2 : key;
    }
  }
#pragma unroll
  for (int w = 32; w > 0; w >>= 1) {     // butterfly on full waves 0,1
    unsigned int lo = (unsigned int)(key & 0xFFFFFFFFull);
    unsigned int hi = (unsigned int)(key >> 32);
    unsigned int lo2 = __shfl_xor(lo, w);
    unsigned int hi2 = __shfl_xor(hi, w);
    unsigned long long other = ((unsigned long long)hi2 << 32) | lo2;
    key = (other < key) ? other : key;
  }
  if ((tid & 63) == 0) atomicMin(cell, key);     // one per wave; same min
}

// Final GEMM (v4 TM=64 body), 1D grid with 8x8-per-XCD block tiling:
// xcd=bid&7 -> (tx,ty)=(xcd&1,xcd>>1); bx=tx*8+(l&7), by=ty*8+(l>>3).
// Per-XCD working set: 2MB y rows + 2MB out_w cols = L2-resident.
__global__ __launch_bounds__(256) void sgemm_nt_v4_64(
    const float* __restrict__ A, const float* __restrict__ Bw,
    float* __restrict__ Cm, int M, int N, int Kd) {
  int bid = blockIdx.x;                  // 0..511
  int xcd = bid & 7;
  int l   = bid >> 3;                    // 0..63
  int bx  = (xcd & 1) * 8 + (l & 7);     // 0..15
  int by  = (xcd >> 1) * 8 + (l >> 3);   // 0..31
  sgemm_body<64>(A, Bw, nullptr, Cm, M, N, Kd, bx, by);
}

// ---------------------------------------------------------------------------
// Kernel 3: gather v5 (4-s-deep batch — R13 optimum; 8-deep regressed).
// ---------------------------------------------------------------------------
__global__ __launch_bounds__(256) void gather_kernel(
    const float* __restrict__ x, const float* __restrict__ freq_a,
    const float* __restrict__ phase_a, const float* __restrict__ kmat,
    const unsigned long long* __restrict__ cell,
    float* __restrict__ y) {
  int i = blockIdx.x;                 // 0..2047
  int p = ((i & 7) << 8) + (i >> 3);  // XCD-contiguous position mapping
  int b = p / LL;
  int l = p - b * LL;
  int d = threadIdx.x;  // 0..255
  __shared__ float4 s_tab[HH * SS];   // {i0 bits, i1 bits, frac, w}
  unsigned int argmin_idx = (unsigned int)(*cell & 0xFFFFFFFFull);
  const float* xb = x + (size_t)b * LL * CC;
  {
    int slot = d;                     // one slot per thread (256 slots)
    int h = slot >> 5;
    int s = slot & 31;
    float fr = freq_a[p * HH + h];
    float ph = phase_a[p * HH + h];
    float tap = (float)s - 15.5f;                       // FROZEN chain:
    float off = __fadd_rn(ph, __fmul_rn(fr, tap));      // mul rnd, add rnd
    float pos = __fadd_rn((float)l, off);
    pos = fminf(fmaxf(pos, 0.0f), 1023.0f);
    float i0f = floorf(pos);
    float frac = __fsub_rn(pos, i0f);
    int i0 = (int)i0f;
    int i1 = min(i0 + 1, LL - 1);
    float dc = __fmul_rn(__fadd_rn(off, 256.0f), 0.125f);
    float fl = floorf(dc);
    float t  = __fsub_rn(dc, fl);
    int bin  = max(0, min((int)fl, KK - 1));
    unsigned int packed = (unsigned int)((p << 8) | slot);
    if (packed == argmin_idx) {
      int altr = (t < 0.5f) ? (int)fl - 1 : (int)fl + 1;
      bin = max(0, min(altr, KK - 1));      // surgical flip (FROZEN)
    }
    float wv = kmat[((size_t)p * HH + h) * KK + bin];
    s_tab[slot] = make_float4(__int_as_float(i0), __int_as_float(i1), frac, wv);
  }
  __syncthreads();
  int q = d & 31;             // d-quad: covers d = q*4 .. q*4+3
  int h = d >> 5;             // one head per thread (0..7)
  const int hb = h * SS;
  const float* xh = xb + h * DD + q * 4;
  float4 acc = make_float4(0.f, 0.f, 0.f, 0.f);

#define LERP_FMA(TB, G0, G1)                                               \
  {                                                                        \
    float frac = TB.z;                                                     \
    float w = TB.w;                                                        \
    float gx = __fadd_rn(G0.x, __fmul_rn(frac, __fsub_rn(G1.x, G0.x)));    \
    float gy = __fadd_rn(G0.y, __fmul_rn(frac, __fsub_rn(G1.y, G0.y)));    \
    float gz = __fadd_rn(G0.z, __fmul_rn(frac, __fsub_rn(G1.z, G0.z)));    \
    float gw = __fadd_rn(G0.w, __fmul_rn(frac, __fsub_rn(G1.w, G0.w)));    \
    acc.x = __fmaf_rn(w, gx, acc.x);                                       \
    acc.y = __fmaf_rn(w, gy, acc.y);                                       \
    acc.z = __fmaf_rn(w, gz, acc.z);                                       \
    acc.w = __fmaf_rn(w, gw, acc.w);                                       \
  }

#pragma unroll
  for (int sg = 0; sg < SS; sg += 4) {
    // batch: 4 tab reads, then 8 global loads in flight, then consume
    float4 tb0 = s_tab[hb + sg + 0];
    float4 tb1 = s_tab[hb + sg + 1];
    float4 tb2 = s_tab[hb + sg + 2];
    float4 tb3 = s_tab[hb + sg + 3];
    float4 g00 = *(const float4*)&xh[(size_t)__float_as_int(tb0.x) * CC];
    float4 g01 = *(const float4*)&xh[(size_t)__float_as_int(tb0.y) * CC];
    float4 g10 = *(const float4*)&xh[(size_t)__float_as_int(tb1.x) * CC];
    float4 g11 = *(const float4*)&xh[(size_t)__float_as_int(tb1.y) * CC];
    float4 g20 = *(const float4*)&xh[(size_t)__float_as_int(tb2.x) * CC];
    float4 g21 = *(const float4*)&xh[(size_t)__float_as_int(tb2.y) * CC];
    float4 g30 = *(const float4*)&xh[(size_t)__float_as_int(tb3.x) * CC];
    float4 g31 = *(const float4*)&xh[(size_t)__float_as_int(tb3.y) * CC];
    LERP_FMA(tb0, g00, g01)              // s ascending — FROZEN chain
    LERP_FMA(tb1, g10, g11)
    LERP_FMA(tb2, g20, g21)
    LERP_FMA(tb3, g30, g31)
  }
#undef LERP_FMA
  *(float4*)&y[(size_t)p * CC + h * DD + q * 4] = acc;
}

// ---------------------------------------------------------------------------
extern "C" void kernel_launch(void* const* d_in, const int* in_sizes, int n_in,
                              void* d_out, int out_size, void* d_ws, size_t ws_size,
                              hipStream_t stream) {
  const float* x        = (const float*)d_in[0];
  const float* wave_w   = (const float*)d_in[1];
  const float* wave_b   = (const float*)d_in[2];
  const float* kernel_w = (const float*)d_in[3];
  const float* kernel_b = (const float*)d_in[4];
  const float* out_w    = (const float*)d_in[5];
  float* out = (float*)d_out;

  float* freq  = (float*)d_ws;                         // 16384 floats
  float* phase = freq + BB * LL * HH;                  // 16384 floats
  unsigned long long* cell =
      (unsigned long long*)(phase + BB * LL * HH);     // 1 u64 (8B aligned)
  float* kmat  = (float*)(cell + 1);                   // 1M floats (4 MB)
  float* y     = kmat + (size_t)BB * LL * HH * KK;     // 2M floats (8 MB)

  const int M = BB * LL;  // 2048

  hipMemsetAsync(cell, 0xFF, sizeof(unsigned long long), stream);  // ~0ULL

  fused_wave_sgemm<<<768, 256, 0, stream>>>(
      x, wave_w, wave_b, freq, phase, cell,
      kernel_w, kernel_b, kmat, M, HH * KK, CC);

  gather_kernel<<<M, 256, 0, stream>>>(x, freq, phase, kmat, cell, y);

  sgemm_nt_v4_64<<<512, 256, 0, stream>>>(y, out_w, out, M, CC, CC);
}